// Round 1
// baseline (1368.613 us; speedup 1.0000x reference)
//
#include <hip/hip_runtime.h>

// Problem constants (fixed by the reference)
#define HID 2048
#define SEQ 2048
#define NB 2
#define NHD 16
#define HD 128
#define FF 5632
#define MROWS 4096  // NB*SEQ

typedef __bf16 bf16x8 __attribute__((ext_vector_type(8)));
typedef float f32x4 __attribute__((ext_vector_type(4)));
typedef unsigned short u16;
typedef unsigned int u32;
typedef unsigned long long u64;

__device__ __forceinline__ u16 f2bf(float f) {
  u32 u = __float_as_uint(f);
  u += 0x7fffu + ((u >> 16) & 1u);   // RNE
  return (u16)(u >> 16);
}
__device__ __forceinline__ float bf2f(u16 h) {
  return __uint_as_float(((u32)h) << 16);
}
__device__ __forceinline__ void gld16(const void* g, void* l) {
  // async global->LDS, 16B per lane; LDS dest = wave-uniform base + lane*16
  __builtin_amdgcn_global_load_lds((__attribute__((address_space(1))) void*)g,
                                   (__attribute__((address_space(3))) void*)l, 16, 0, 0);
}

// ---------------- RMSNorm: fp32 [rows][2048] -> bf16 ----------------
__global__ __launch_bounds__(256) void rmsnorm_k(const float* __restrict__ x,
                                                 const float* __restrict__ sc,
                                                 u16* __restrict__ out) {
  __shared__ float red[4];
  const int row = blockIdx.x, t = threadIdx.x;
  const float4* xr = (const float4*)(x + (size_t)row * HID);
  float4 a = xr[t], b = xr[t + 256];
  float ss = a.x*a.x + a.y*a.y + a.z*a.z + a.w*a.w
           + b.x*b.x + b.y*b.y + b.z*b.z + b.w*b.w;
#pragma unroll
  for (int o = 1; o < 64; o <<= 1) ss += __shfl_xor(ss, o);
  if ((t & 63) == 0) red[t >> 6] = ss;
  __syncthreads();
  float tot = red[0] + red[1] + red[2] + red[3];
  float r = rsqrtf(tot * (1.0f / HID) + 1e-5f);
  const float4* scp = (const float4*)sc;
  float4 s0 = scp[t], s1 = scp[t + 256];
  u32 p0 = (u32)f2bf(a.x*r*s0.x) | ((u32)f2bf(a.y*r*s0.y) << 16);
  u32 p1 = (u32)f2bf(a.z*r*s0.z) | ((u32)f2bf(a.w*r*s0.w) << 16);
  u32 p2 = (u32)f2bf(b.x*r*s1.x) | ((u32)f2bf(b.y*r*s1.y) << 16);
  u32 p3 = (u32)f2bf(b.z*r*s1.z) | ((u32)f2bf(b.w*r*s1.w) << 16);
  u32* op = (u32*)(out + (size_t)row * HID);
  op[t*2] = p0; op[t*2+1] = p1;
  op[512 + t*2] = p2; op[512 + t*2 + 1] = p3;
}

// ------------- transpose+convert: fp32 W[R][C] -> bf16 Wt[C][R] -------------
__global__ __launch_bounds__(256) void transpose_cvt_k(const float* __restrict__ W,
                                                       u16* __restrict__ Wt,
                                                       int R, int C) {
  __shared__ float tile[32][33];
  const int tx = threadIdx.x & 31, ty = threadIdx.x >> 5;
  const int bc = blockIdx.x * 32, br = blockIdx.y * 32;
#pragma unroll
  for (int i = 0; i < 4; ++i)
    tile[ty + i*8][tx] = W[(size_t)(br + ty + i*8) * C + bc + tx];
  __syncthreads();
#pragma unroll
  for (int i = 0; i < 4; ++i)
    Wt[(size_t)(bc + ty + i*8) * R + br + tx] = f2bf(tile[tx][ty + i*8]);
}

// ---------------- RoPE in place on [B*H][S][D] bf16 ----------------
__global__ __launch_bounds__(256) void rope_k(u16* __restrict__ qk, const int* __restrict__ pos) {
  const u32 i = blockIdx.x * 256 + threadIdx.x;  // B*H*S*64 pairs
  const int d2 = i & 63;
  const int s = (i >> 6) & 2047;
  const int bh = i >> 17;
  const int b = bh >> 4;
  const float p = (float)pos[(size_t)b * SEQ + s];
  // inv_freq = theta^(-d2/64) = 2^(-d2 * log2(theta)/64)
  const float ang = p * exp2f(-(float)d2 * 0.2958057589f);
  float sv, cv;
  sincosf(ang, &sv, &cv);
  u32* ptr = (u32*)(qk + ((size_t)bh * SEQ + s) * HD) + d2;
  u32 u = *ptr;
  float x0 = bf2f((u16)(u & 0xffff)), x1 = bf2f((u16)(u >> 16));
  float o0 = x0 * cv - x1 * sv;
  float o1 = x1 * cv + x0 * sv;
  *ptr = (u32)f2bf(o0) | ((u32)f2bf(o1) << 16);
}

// ---------------- GEMM: C[M][N] = A[M][K] * Bt[N][K]^T, bf16 in, fp32 acc ----------------
// m97 structure: 128x128 tile, 4 waves of 64x64, BK=32, global_load_lds staging.
// EPI: 1 = scatter bf16 to [B,H,S,D]; 2 = fp32 out = addsrc + acc;
//      3 = bf16 out = silu(acc);     4 = bf16 out = bf2f(mulsrc)*acc (in-place ok)
//      5 = scatter bf16 TRANSPOSED to [B,H,D,S] (for V)
template <int EPI>
__global__ __launch_bounds__(256, 2) void gemm_k(const u16* __restrict__ A,
                                                 const u16* __restrict__ Bt,
                                                 int N, int K,
                                                 const float* addsrc,
                                                 const u16* mulsrc,
                                                 void* outp) {
  __shared__ __align__(16) u16 As[128 * 32];
  __shared__ __align__(16) u16 Bs[128 * 32];
  const int tid = threadIdx.x, lane = tid & 63, wid = tid >> 6;
  const int lr = lane & 15, lg = lane >> 4;
  const int wr = wid >> 1, wc = wid & 1;
  const int mt = blockIdx.y * 128, nt = blockIdx.x * 128;

  const f32x4 fz = {0.f, 0.f, 0.f, 0.f};
  f32x4 acc[4][4];
#pragma unroll
  for (int i = 0; i < 4; ++i)
#pragma unroll
    for (int j = 0; j < 4; ++j) acc[i][j] = fz;

  // staging mapping: chunk = wid*2+c (1KB each); lane's element e = chunk*512 + lane*8
  const int r0 = wid * 32 + (lane >> 2);     // chunk0 row
  const int c0 = (lane & 3) * 8;             // chunk0 col
  u16* ldsA0 = As + wid * 1024;              // wave-uniform bases
  u16* ldsA1 = As + wid * 1024 + 512;
  u16* ldsB0 = Bs + wid * 1024;
  u16* ldsB1 = Bs + wid * 1024 + 512;
  const u16* Abase = A + (size_t)mt * K;
  const u16* Bbase = Bt + (size_t)nt * K;

  for (int kt = 0; kt < K; kt += 32) {
    gld16(Abase + (size_t)r0 * K + kt + c0, ldsA0);
    gld16(Abase + (size_t)(r0 + 16) * K + kt + c0, ldsA1);
    gld16(Bbase + (size_t)r0 * K + kt + c0, ldsB0);
    gld16(Bbase + (size_t)(r0 + 16) * K + kt + c0, ldsB1);
    __syncthreads();
    bf16x8 af[4], bfr[4];
#pragma unroll
    for (int mi = 0; mi < 4; ++mi)
      af[mi] = *(const bf16x8*)(As + (wr * 64 + mi * 16 + lr) * 32 + lg * 8);
#pragma unroll
    for (int ni = 0; ni < 4; ++ni)
      bfr[ni] = *(const bf16x8*)(Bs + (wc * 64 + ni * 16 + lr) * 32 + lg * 8);
#pragma unroll
    for (int mi = 0; mi < 4; ++mi)
#pragma unroll
      for (int ni = 0; ni < 4; ++ni)
        acc[mi][ni] = __builtin_amdgcn_mfma_f32_16x16x32_bf16(af[mi], bfr[ni], acc[mi][ni], 0, 0, 0);
    __syncthreads();
  }

#pragma unroll
  for (int mi = 0; mi < 4; ++mi) {
#pragma unroll
    for (int ni = 0; ni < 4; ++ni) {
      const int gr0 = mt + wr * 64 + mi * 16 + lg * 4;
      const int gc = nt + wc * 64 + ni * 16 + lr;
      f32x4 v = acc[mi][ni];
      if (EPI == 5) {
        // V^T layout [B,H,D,S]; 4 consecutive s rows -> one 8B store
        const int b = gr0 >> 11, s = gr0 & 2047, hh = gc >> 7, d = gc & 127;
        u64 pk = (u64)f2bf(v[0])
               | ((u64)f2bf(v[1]) << 16)
               | ((u64)f2bf(v[2]) << 32)
               | ((u64)f2bf(v[3]) << 48);
        *(u64*)((u16*)outp + ((((size_t)(b * NHD + hh)) * HD + d) << 11) + s) = pk;
      } else {
#pragma unroll
        for (int r = 0; r < 4; ++r) {
          const int gr = gr0 + r;
          const float val = v[r];
          if (EPI == 1) {
            const int b = gr >> 11, s = gr & 2047, hh = gc >> 7, d = gc & 127;
            ((u16*)outp)[((((size_t)(b * NHD + hh)) * SEQ + s) << 7) + d] = f2bf(val);
          } else if (EPI == 2) {
            const size_t o = (size_t)gr * N + gc;
            ((float*)outp)[o] = addsrc[o] + val;
          } else if (EPI == 3) {
            const size_t o = (size_t)gr * N + gc;
            ((u16*)outp)[o] = f2bf(val / (1.f + __expf(-val)));
          } else if (EPI == 4) {
            const size_t o = (size_t)gr * N + gc;
            ((u16*)outp)[o] = f2bf(bf2f(mulsrc[o]) * val);
          }
        }
      }
    }
  }
}

// ---------------- Flash attention, causal, bf16 ----------------
// Q,K in [B*H][S][D]; V in [B*H][D][S] (transposed by gemm_k<5>).
// No K/V LDS staging (K/V per head = 1MB, L2-resident), no __syncthreads.
// 4 independent waves x 16 q-rows, KV tile = 64 keys. Only LDS use: per-wave
// P round-trip (same-wave write->read, lgkmcnt fence).
__global__ __launch_bounds__(256, 4) void attn_k(const u16* __restrict__ Q,
                                                 const u16* __restrict__ Kg,
                                                 const u16* __restrict__ Vtg,
                                                 u16* __restrict__ out) {
  __shared__ __align__(16) u16 Pl[4][16 * 72];  // per-wave P [q][key], stride 72
  const int tid = threadIdx.x, lane = tid & 63, wid = tid >> 6;
  const int lr = lane & 15, lg = lane >> 4;
  // XCD swizzle (1024 blocks, %8==0 -> simple form bijective): each XCD gets
  // 4 whole heads -> K/V stay L2-local; causal load spread evenly per XCD.
  int wg = blockIdx.x;
  wg = (wg & 7) * 128 + (wg >> 3);
  const int qt = wg & 31, bh = wg >> 5;
  const size_t bhoff = (size_t)bh * SEQ * HD;
  const u16* Qp = Q + bhoff;
  const u16* Kp = Kg + bhoff;
  const u16* Vp = Vtg + bhoff;   // [D][S]
  const int qrow0 = qt * 64 + wid * 16;

  bf16x8 qf[4];
#pragma unroll
  for (int t = 0; t < 4; ++t)
    qf[t] = *(const bf16x8*)(Qp + (size_t)(qrow0 + lr) * HD + t * 32 + lg * 8);

  const f32x4 fz = {0.f, 0.f, 0.f, 0.f};
  f32x4 o[8];
#pragma unroll
  for (int i = 0; i < 8; ++i) o[i] = fz;
  float mrun[4] = {-1e30f, -1e30f, -1e30f, -1e30f};
  float lrun[4] = {0.f, 0.f, 0.f, 0.f};
  const float scale = 0.08838834764831845f;  // 1/sqrt(128)
  u16* Pw = Pl[wid];

  const int kend = qt * 64 + 64;
  for (int kt = 0; kt < kend; kt += 64) {
    // ---- QK^T: K fragments straight from global (16B/lane, L2-hit) ----
    f32x4 sc[4];
#pragma unroll
    for (int nh = 0; nh < 4; ++nh) {
      f32x4 s = fz;
      const u16* kp = Kp + (size_t)(kt + nh * 16 + lr) * HD + lg * 8;
#pragma unroll
      for (int t = 0; t < 4; ++t) {
        bf16x8 kf = *(const bf16x8*)(kp + t * 32);
        s = __builtin_amdgcn_mfma_f32_16x16x32_bf16(qf[t], kf, s, 0, 0, 0);
      }
      sc[nh] = s;
    }
    // ---- online softmax over 64 keys (4 groups of 16 lanes) ----
    float pv[4][4], alpha[4];
#pragma unroll
    for (int r = 0; r < 4; ++r) {
      const int qrow = qrow0 + lg * 4 + r;
      float s0 = sc[0][r] * scale;
      float s1 = sc[1][r] * scale;
      float s2 = sc[2][r] * scale;
      float s3 = sc[3][r] * scale;
      if (kt + lr > qrow)      s0 = -1e30f;
      if (kt + 16 + lr > qrow) s1 = -1e30f;
      if (kt + 32 + lr > qrow) s2 = -1e30f;
      if (kt + 48 + lr > qrow) s3 = -1e30f;
      float mx = fmaxf(fmaxf(s0, s1), fmaxf(s2, s3));
      mx = fmaxf(mx, __shfl_xor(mx, 1));
      mx = fmaxf(mx, __shfl_xor(mx, 2));
      mx = fmaxf(mx, __shfl_xor(mx, 4));
      mx = fmaxf(mx, __shfl_xor(mx, 8));
      const float mn = fmaxf(mrun[r], mx);
      const float p0 = __expf(s0 - mn), p1 = __expf(s1 - mn);
      const float p2 = __expf(s2 - mn), p3 = __expf(s3 - mn);
      float ts = p0 + p1 + p2 + p3;
      ts += __shfl_xor(ts, 1);
      ts += __shfl_xor(ts, 2);
      ts += __shfl_xor(ts, 4);
      ts += __shfl_xor(ts, 8);
      const float al = __expf(mrun[r] - mn);
      alpha[r] = al;
      lrun[r] = lrun[r] * al + ts;
      mrun[r] = mn;
      pv[0][r] = p0; pv[1][r] = p1; pv[2][r] = p2; pv[3][r] = p3;
    }
#pragma unroll
    for (int i = 0; i < 8; ++i) {
      o[i][0] *= alpha[0]; o[i][1] *= alpha[1];
      o[i][2] *= alpha[2]; o[i][3] *= alpha[3];
    }
    // ---- P -> LDS (lane redistribution for MFMA A-operand) ----
#pragma unroll
    for (int nh = 0; nh < 4; ++nh)
#pragma unroll
      for (int r = 0; r < 4; ++r)
        Pw[(lg * 4 + r) * 72 + nh * 16 + lr] = f2bf(pv[nh][r]);
    asm volatile("s_waitcnt lgkmcnt(0)\n" ::: "memory");  // P write -> read, same wave
    const bf16x8 pf0 = *(const bf16x8*)(Pw + lr * 72 + lg * 8);
    const bf16x8 pf1 = *(const bf16x8*)(Pw + lr * 72 + 32 + lg * 8);
    // ---- PV: V^T fragments straight from global (16B/lane, L2-hit) ----
#pragma unroll
    for (int nt = 0; nt < 8; ++nt) {
      const u16* vp = Vp + (size_t)(nt * 16 + lr) * SEQ + kt + lg * 8;
      bf16x8 v0 = *(const bf16x8*)vp;
      bf16x8 v1 = *(const bf16x8*)(vp + 32);
      o[nt] = __builtin_amdgcn_mfma_f32_16x16x32_bf16(pf0, v0, o[nt], 0, 0, 0);
      o[nt] = __builtin_amdgcn_mfma_f32_16x16x32_bf16(pf1, v1, o[nt], 0, 0, 0);
    }
  }

  const int b = bh >> 4, h = bh & 15;
#pragma unroll
  for (int r = 0; r < 4; ++r) {
    const int q = qrow0 + lg * 4 + r;
    const float inv = 1.f / lrun[r];
    u16* op = out + ((size_t)(b * SEQ + q)) * HID + h * HD + lr;
#pragma unroll
    for (int nt = 0; nt < 8; ++nt)
      op[nt * 16] = f2bf(o[nt][r] * inv);
  }
}

extern "C" void kernel_launch(void* const* d_in, const int* in_sizes, int n_in,
                              void* d_out, int out_size, void* d_ws, size_t ws_size,
                              hipStream_t stream) {
  (void)in_sizes; (void)n_in; (void)out_size; (void)ws_size;
  const float* x   = (const float*)d_in[0];
  const int*   pos = (const int*)d_in[1];
  // d_in[2] = mask: causal tril by construction — handled analytically
  const float* wq  = (const float*)d_in[3];
  const float* wk  = (const float*)d_in[4];
  const float* wv  = (const float*)d_in[5];
  const float* wo  = (const float*)d_in[6];
  const float* asc = (const float*)d_in[7];
  const float* fsc = (const float*)d_in[8];
  const float* w1  = (const float*)d_in[9];
  const float* w3  = (const float*)d_in[10];
  const float* w2  = (const float*)d_in[11];
  float* out = (float*)d_out;

  // workspace carve (130 MB total)
  char* ws = (char*)d_ws;
  u16* qb = (u16*)ws; ws += (size_t)MROWS * HID * 2;   // Q [B,H,S,D]
  u16* kb = (u16*)ws; ws += (size_t)MROWS * HID * 2;   // K [B,H,S,D]
  u16* vb = (u16*)ws; ws += (size_t)MROWS * HID * 2;   // V^T [B,H,D,S]
  u16* xb = (u16*)ws; ws += (size_t)MROWS * HID * 2;   // x_norm / attn_out / ff (bf16)
  u16* gb = (u16*)ws; ws += (size_t)MROWS * FF * 2;    // g1 / u (bf16)
  u16* wb = (u16*)ws; ws += (size_t)FF * HID * 2;      // current transposed weight (bf16)

  dim3 b256(256);

  rmsnorm_k<<<MROWS, b256, 0, stream>>>(x, asc, xb);

  transpose_cvt_k<<<dim3(HID/32, HID/32), b256, 0, stream>>>(wq, wb, HID, HID);
  gemm_k<1><<<dim3(HID/128, MROWS/128), b256, 0, stream>>>(xb, wb, HID, HID, nullptr, nullptr, qb);
  transpose_cvt_k<<<dim3(HID/32, HID/32), b256, 0, stream>>>(wk, wb, HID, HID);
  gemm_k<1><<<dim3(HID/128, MROWS/128), b256, 0, stream>>>(xb, wb, HID, HID, nullptr, nullptr, kb);
  transpose_cvt_k<<<dim3(HID/32, HID/32), b256, 0, stream>>>(wv, wb, HID, HID);
  gemm_k<5><<<dim3(HID/128, MROWS/128), b256, 0, stream>>>(xb, wb, HID, HID, nullptr, nullptr, vb);

  rope_k<<<(NB*NHD*SEQ*(HD/2))/256, b256, 0, stream>>>(qb, pos);
  rope_k<<<(NB*NHD*SEQ*(HD/2))/256, b256, 0, stream>>>(kb, pos);

  attn_k<<<dim3(1024), b256, 0, stream>>>(qb, kb, vb, xb);

  transpose_cvt_k<<<dim3(HID/32, HID/32), b256, 0, stream>>>(wo, wb, HID, HID);
  gemm_k<2><<<dim3(HID/128, MROWS/128), b256, 0, stream>>>(xb, wb, HID, HID, x, nullptr, out);  // h

  rmsnorm_k<<<MROWS, b256, 0, stream>>>(out, fsc, xb);  // ff

  transpose_cvt_k<<<dim3(FF/32, HID/32), b256, 0, stream>>>(w1, wb, HID, FF);
  gemm_k<3><<<dim3(FF/128, MROWS/128), b256, 0, stream>>>(xb, wb, FF, HID, nullptr, nullptr, gb);  // silu(ff@w1)
  transpose_cvt_k<<<dim3(FF/32, HID/32), b256, 0, stream>>>(w3, wb, HID, FF);
  gemm_k<4><<<dim3(FF/128, MROWS/128), b256, 0, stream>>>(xb, wb, FF, HID, nullptr, gb, gb);      // u = silu*g3
  transpose_cvt_k<<<dim3(HID/32, FF/32), b256, 0, stream>>>(w2, wb, FF, HID);
  gemm_k<2><<<dim3(HID/128, MROWS/128), b256, 0, stream>>>(gb, wb, HID, FF, out, nullptr, out);   // out = h + u@w2
}

// Round 2
// 1002.796 us; speedup vs baseline: 1.3648x; 1.3648x over previous
//
#include <hip/hip_runtime.h>

// Problem constants (fixed by the reference)
#define HID 2048
#define SEQ 2048
#define NB 2
#define NHD 16
#define HD 128
#define FF 5632
#define MROWS 4096  // NB*SEQ

typedef __bf16 bf16x8 __attribute__((ext_vector_type(8)));
typedef float f32x4 __attribute__((ext_vector_type(4)));
typedef unsigned short u16;
typedef unsigned int u32;
typedef unsigned long long u64;

__device__ __forceinline__ u16 f2bf(float f) {
  u32 u = __float_as_uint(f);
  u += 0x7fffu + ((u >> 16) & 1u);   // RNE
  return (u16)(u >> 16);
}
__device__ __forceinline__ float bf2f(u16 h) {
  return __uint_as_float(((u32)h) << 16);
}
__device__ __forceinline__ void gld16(const void* g, void* l) {
  // async global->LDS, 16B per lane; LDS dest = wave-uniform base + lane*16
  __builtin_amdgcn_global_load_lds((__attribute__((address_space(1))) void*)g,
                                   (__attribute__((address_space(3))) void*)l, 16, 0, 0);
}

// ---------------- RMSNorm: fp32 [rows][2048] -> bf16 ----------------
__global__ __launch_bounds__(256) void rmsnorm_k(const float* __restrict__ x,
                                                 const float* __restrict__ sc,
                                                 u16* __restrict__ out) {
  __shared__ float red[4];
  const int row = blockIdx.x, t = threadIdx.x;
  const float4* xr = (const float4*)(x + (size_t)row * HID);
  float4 a = xr[t], b = xr[t + 256];
  float ss = a.x*a.x + a.y*a.y + a.z*a.z + a.w*a.w
           + b.x*b.x + b.y*b.y + b.z*b.z + b.w*b.w;
#pragma unroll
  for (int o = 1; o < 64; o <<= 1) ss += __shfl_xor(ss, o);
  if ((t & 63) == 0) red[t >> 6] = ss;
  __syncthreads();
  float tot = red[0] + red[1] + red[2] + red[3];
  float r = rsqrtf(tot * (1.0f / HID) + 1e-5f);
  const float4* scp = (const float4*)sc;
  float4 s0 = scp[t], s1 = scp[t + 256];
  u32 p0 = (u32)f2bf(a.x*r*s0.x) | ((u32)f2bf(a.y*r*s0.y) << 16);
  u32 p1 = (u32)f2bf(a.z*r*s0.z) | ((u32)f2bf(a.w*r*s0.w) << 16);
  u32 p2 = (u32)f2bf(b.x*r*s1.x) | ((u32)f2bf(b.y*r*s1.y) << 16);
  u32 p3 = (u32)f2bf(b.z*r*s1.z) | ((u32)f2bf(b.w*r*s1.w) << 16);
  u32* op = (u32*)(out + (size_t)row * HID);
  op[t*2] = p0; op[t*2+1] = p1;
  op[512 + t*2] = p2; op[512 + t*2 + 1] = p3;
}

// ------------- transpose+convert: fp32 W[R][C] -> bf16 Wt[C][R] -------------
__global__ __launch_bounds__(256) void transpose_cvt_k(const float* __restrict__ W,
                                                       u16* __restrict__ Wt,
                                                       int R, int C) {
  __shared__ float tile[32][33];
  const int tx = threadIdx.x & 31, ty = threadIdx.x >> 5;
  const int bc = blockIdx.x * 32, br = blockIdx.y * 32;
#pragma unroll
  for (int i = 0; i < 4; ++i)
    tile[ty + i*8][tx] = W[(size_t)(br + ty + i*8) * C + bc + tx];
  __syncthreads();
#pragma unroll
  for (int i = 0; i < 4; ++i)
    Wt[(size_t)(bc + ty + i*8) * R + br + tx] = f2bf(tile[tx][ty + i*8]);
}

// ---------------- RoPE in place on [B*H][S][D] bf16 ----------------
__global__ __launch_bounds__(256) void rope_k(u16* __restrict__ qk, const int* __restrict__ pos) {
  const u32 i = blockIdx.x * 256 + threadIdx.x;  // B*H*S*64 pairs
  const int d2 = i & 63;
  const int s = (i >> 6) & 2047;
  const int bh = i >> 17;
  const int b = bh >> 4;
  const float p = (float)pos[(size_t)b * SEQ + s];
  // inv_freq = theta^(-d2/64) = 2^(-d2 * log2(theta)/64)
  const float ang = p * exp2f(-(float)d2 * 0.2958057589f);
  float sv, cv;
  sincosf(ang, &sv, &cv);
  u32* ptr = (u32*)(qk + ((size_t)bh * SEQ + s) * HD) + d2;
  u32 u = *ptr;
  float x0 = bf2f((u16)(u & 0xffff)), x1 = bf2f((u16)(u >> 16));
  float o0 = x0 * cv - x1 * sv;
  float o1 = x1 * cv + x0 * sv;
  *ptr = (u32)f2bf(o0) | ((u32)f2bf(o1) << 16);
}

// ---------------- GEMM: C[M][N] = A[M][K] * Bt[N][K]^T, bf16 in, fp32 acc ----------------
// m97 structure: 128x128 tile, 4 waves of 64x64, BK=32, global_load_lds staging.
// EPI: 1 = scatter bf16 to [B,H,S,D]; 2 = fp32 out = addsrc + acc;
//      3 = bf16 out = silu(acc);     4 = bf16 out = bf2f(mulsrc)*acc (in-place ok)
//      5 = scatter bf16 TRANSPOSED to [B,H,D,S] (for V)
template <int EPI>
__global__ __launch_bounds__(256, 2) void gemm_k(const u16* __restrict__ A,
                                                 const u16* __restrict__ Bt,
                                                 int N, int K,
                                                 const float* addsrc,
                                                 const u16* mulsrc,
                                                 void* outp) {
  __shared__ __align__(16) u16 As[128 * 32];
  __shared__ __align__(16) u16 Bs[128 * 32];
  const int tid = threadIdx.x, lane = tid & 63, wid = tid >> 6;
  const int lr = lane & 15, lg = lane >> 4;
  const int wr = wid >> 1, wc = wid & 1;
  const int mt = blockIdx.y * 128, nt = blockIdx.x * 128;

  const f32x4 fz = {0.f, 0.f, 0.f, 0.f};
  f32x4 acc[4][4];
#pragma unroll
  for (int i = 0; i < 4; ++i)
#pragma unroll
    for (int j = 0; j < 4; ++j) acc[i][j] = fz;

  // staging mapping: chunk = wid*2+c (1KB each); lane's element e = chunk*512 + lane*8
  const int r0 = wid * 32 + (lane >> 2);     // chunk0 row
  const int c0 = (lane & 3) * 8;             // chunk0 col
  u16* ldsA0 = As + wid * 1024;              // wave-uniform bases
  u16* ldsA1 = As + wid * 1024 + 512;
  u16* ldsB0 = Bs + wid * 1024;
  u16* ldsB1 = Bs + wid * 1024 + 512;
  const u16* Abase = A + (size_t)mt * K;
  const u16* Bbase = Bt + (size_t)nt * K;

  for (int kt = 0; kt < K; kt += 32) {
    gld16(Abase + (size_t)r0 * K + kt + c0, ldsA0);
    gld16(Abase + (size_t)(r0 + 16) * K + kt + c0, ldsA1);
    gld16(Bbase + (size_t)r0 * K + kt + c0, ldsB0);
    gld16(Bbase + (size_t)(r0 + 16) * K + kt + c0, ldsB1);
    __syncthreads();
    bf16x8 af[4], bfr[4];
#pragma unroll
    for (int mi = 0; mi < 4; ++mi)
      af[mi] = *(const bf16x8*)(As + (wr * 64 + mi * 16 + lr) * 32 + lg * 8);
#pragma unroll
    for (int ni = 0; ni < 4; ++ni)
      bfr[ni] = *(const bf16x8*)(Bs + (wc * 64 + ni * 16 + lr) * 32 + lg * 8);
#pragma unroll
    for (int mi = 0; mi < 4; ++mi)
#pragma unroll
      for (int ni = 0; ni < 4; ++ni)
        acc[mi][ni] = __builtin_amdgcn_mfma_f32_16x16x32_bf16(af[mi], bfr[ni], acc[mi][ni], 0, 0, 0);
    __syncthreads();
  }

#pragma unroll
  for (int mi = 0; mi < 4; ++mi) {
#pragma unroll
    for (int ni = 0; ni < 4; ++ni) {
      const int gr0 = mt + wr * 64 + mi * 16 + lg * 4;
      const int gc = nt + wc * 64 + ni * 16 + lr;
      f32x4 v = acc[mi][ni];
      if (EPI == 5) {
        // V^T layout [B,H,D,S]; 4 consecutive s rows -> one 8B store
        const int b = gr0 >> 11, s = gr0 & 2047, hh = gc >> 7, d = gc & 127;
        u64 pk = (u64)f2bf(v[0])
               | ((u64)f2bf(v[1]) << 16)
               | ((u64)f2bf(v[2]) << 32)
               | ((u64)f2bf(v[3]) << 48);
        *(u64*)((u16*)outp + ((((size_t)(b * NHD + hh)) * HD + d) << 11) + s) = pk;
      } else {
#pragma unroll
        for (int r = 0; r < 4; ++r) {
          const int gr = gr0 + r;
          const float val = v[r];
          if (EPI == 1) {
            const int b = gr >> 11, s = gr & 2047, hh = gc >> 7, d = gc & 127;
            ((u16*)outp)[((((size_t)(b * NHD + hh)) * SEQ + s) << 7) + d] = f2bf(val);
          } else if (EPI == 2) {
            const size_t o = (size_t)gr * N + gc;
            ((float*)outp)[o] = addsrc[o] + val;
          } else if (EPI == 3) {
            const size_t o = (size_t)gr * N + gc;
            ((u16*)outp)[o] = f2bf(val / (1.f + __expf(-val)));
          } else if (EPI == 4) {
            const size_t o = (size_t)gr * N + gc;
            ((u16*)outp)[o] = f2bf(bf2f(mulsrc[o]) * val);
          }
        }
      }
    }
  }
}

// ---------------- Flash attention, causal, bf16 ----------------
// Q,K in [B*H][S][D]; V in [B*H][D][S] (transposed by gemm_k<5>).
// Structure: 512 blocks x 4 waves; block handles q-tile pair (p, 31-p) of one
// head -> uniform 33 key-tiles/block, 2 blocks/CU all-resident (no drain tail).
// K and V^T tiles (64 keys) double-buffered in LDS via global_load_lds with
// XOR-swizzled per-lane SOURCE addresses (LDS dest linear), swizzled ds_reads
// -> 2-way-max bank conflicts. 2-phase: stage t+1, compute t, one barrier.
#define ATT_SW(row) (((row) & 7) << 4)

__device__ __forceinline__ void att_stage(const u16* __restrict__ Kp,
                                          const u16* __restrict__ Vp,
                                          int kt, char* kb, char* vb,
                                          int tid, int wid) {
  // K tile [64 key][128 d] u16 = 16KB: 16 chunks(16B)/row
#pragma unroll
  for (int j = 0; j < 4; ++j) {
    const int c = j * 256 + tid;
    const int row = c >> 4;
    const int scb = ((c & 15) << 4) ^ ATT_SW(row);
    gld16(Kp + (size_t)(kt + row) * HD + (scb >> 1), kb + j * 4096 + wid * 1024);
  }
  // V^T tile [128 d][64 key] u16 = 16KB: 8 chunks/row
#pragma unroll
  for (int j = 0; j < 4; ++j) {
    const int c = j * 256 + tid;
    const int row = c >> 3;
    const int scb = ((c & 7) << 4) ^ ATT_SW(row);
    gld16(Vp + (size_t)row * SEQ + kt + (scb >> 1), vb + j * 4096 + wid * 1024);
  }
}

__global__ __launch_bounds__(256, 2) void attn_k(const u16* __restrict__ Q,
                                                 const u16* __restrict__ Kg,
                                                 const u16* __restrict__ Vtg,
                                                 u16* __restrict__ out) {
  __shared__ __align__(16) char Kb[2][16384];
  __shared__ __align__(16) char Vb[2][16384];
  __shared__ __align__(16) u16 Pl[4][16 * 72];  // per-wave P [q][key], stride 72
  const int tid = threadIdx.x, lane = tid & 63, wid = tid >> 6;
  const int lr = lane & 15, lg = lane >> 4;
  // XCD swizzle: 512 blocks (%8==0 -> bijective); XCD x gets heads [4x,4x+4)
  // -> K+V working set 4MB = L2-fit per XCD.
  int wg = blockIdx.x;
  wg = (wg & 7) * 64 + (wg >> 3);
  const int bh = wg >> 4, pr = wg & 15;
  const size_t bhoff = (size_t)bh * SEQ * HD;
  const u16* Qp = Q + bhoff;
  const u16* Kp = Kg + bhoff;
  const u16* Vp = Vtg + bhoff;   // [D][S]
  const int bb = bh >> 4, hh = bh & 15;
  u16* Pw = Pl[wid];
  const int sw = ATT_SW(lr);
  const float scale = 0.08838834764831845f;  // 1/sqrt(128)
  const f32x4 fz = {0.f, 0.f, 0.f, 0.f};

  for (int side = 0; side < 2; ++side) {
    const int qt = side ? (31 - pr) : pr;
    const int qrow0 = qt * 64 + wid * 16;

    bf16x8 qf[4];
#pragma unroll
    for (int t = 0; t < 4; ++t)
      qf[t] = *(const bf16x8*)(Qp + (size_t)(qrow0 + lr) * HD + t * 32 + lg * 8);

    f32x4 o[8];
#pragma unroll
    for (int i = 0; i < 8; ++i) o[i] = fz;
    float mrun[4] = {-1e30f, -1e30f, -1e30f, -1e30f};
    float lrun[4] = {0.f, 0.f, 0.f, 0.f};

    const int kend = qt * 64 + 64;
    int cur = 0;
    att_stage(Kp, Vp, 0, Kb[0], Vb[0], tid, wid);
    __syncthreads();  // drains vmcnt -> tile 0 staged

    for (int kt = 0; kt < kend; kt += 64) {
      if (kt + 64 < kend)
        att_stage(Kp, Vp, kt + 64, Kb[cur ^ 1], Vb[cur ^ 1], tid, wid);
      const char* kbuf = Kb[cur];
      const char* vbuf = Vb[cur];

      // ---- QK^T from swizzled LDS ----
      f32x4 sc[4];
#pragma unroll
      for (int nh = 0; nh < 4; ++nh) {
        f32x4 s = fz;
#pragma unroll
        for (int t = 0; t < 4; ++t) {
          bf16x8 kf = *(const bf16x8*)(kbuf + (nh * 16 + lr) * 256 + ((t * 64 + lg * 16) ^ sw));
          s = __builtin_amdgcn_mfma_f32_16x16x32_bf16(qf[t], kf, s, 0, 0, 0);
        }
        sc[nh] = s;
      }

      // ---- online softmax over 64 keys (16-lane groups hold keys) ----
      float pv[4][4], alpha[4];
#pragma unroll
      for (int r = 0; r < 4; ++r) {
        const int qrow = qrow0 + lg * 4 + r;
        float s0 = sc[0][r] * scale;
        float s1 = sc[1][r] * scale;
        float s2 = sc[2][r] * scale;
        float s3 = sc[3][r] * scale;
        if (kt + lr > qrow)      s0 = -1e30f;
        if (kt + 16 + lr > qrow) s1 = -1e30f;
        if (kt + 32 + lr > qrow) s2 = -1e30f;
        if (kt + 48 + lr > qrow) s3 = -1e30f;
        float mx = fmaxf(fmaxf(s0, s1), fmaxf(s2, s3));
        mx = fmaxf(mx, __shfl_xor(mx, 1));
        mx = fmaxf(mx, __shfl_xor(mx, 2));
        mx = fmaxf(mx, __shfl_xor(mx, 4));
        mx = fmaxf(mx, __shfl_xor(mx, 8));
        const float mn = fmaxf(mrun[r], mx);
        const float p0 = __expf(s0 - mn), p1 = __expf(s1 - mn);
        const float p2 = __expf(s2 - mn), p3 = __expf(s3 - mn);
        float ts = p0 + p1 + p2 + p3;
        ts += __shfl_xor(ts, 1);
        ts += __shfl_xor(ts, 2);
        ts += __shfl_xor(ts, 4);
        ts += __shfl_xor(ts, 8);
        const float al = __expf(mrun[r] - mn);
        alpha[r] = al;
        lrun[r] = lrun[r] * al + ts;
        mrun[r] = mn;
        pv[0][r] = p0; pv[1][r] = p1; pv[2][r] = p2; pv[3][r] = p3;
      }
#pragma unroll
      for (int i = 0; i < 8; ++i) {
        o[i][0] *= alpha[0]; o[i][1] *= alpha[1];
        o[i][2] *= alpha[2]; o[i][3] *= alpha[3];
      }

      // ---- P -> LDS (lane redistribution for MFMA A-operand) ----
#pragma unroll
      for (int nh = 0; nh < 4; ++nh)
#pragma unroll
        for (int r = 0; r < 4; ++r)
          Pw[(lg * 4 + r) * 72 + nh * 16 + lr] = f2bf(pv[nh][r]);
      asm volatile("s_waitcnt lgkmcnt(0)\n" ::: "memory");  // P write -> read, same wave
      const bf16x8 pf0 = *(const bf16x8*)(Pw + lr * 72 + lg * 8);
      const bf16x8 pf1 = *(const bf16x8*)(Pw + lr * 72 + 32 + lg * 8);

      // ---- PV from swizzled V^T LDS ----
#pragma unroll
      for (int nt = 0; nt < 8; ++nt) {
        const char* vr = vbuf + (nt * 16 + lr) * 128;
        bf16x8 v0 = *(const bf16x8*)(vr + ((lg * 16) ^ sw));
        bf16x8 v1 = *(const bf16x8*)(vr + ((64 + lg * 16) ^ sw));
        o[nt] = __builtin_amdgcn_mfma_f32_16x16x32_bf16(pf0, v0, o[nt], 0, 0, 0);
        o[nt] = __builtin_amdgcn_mfma_f32_16x16x32_bf16(pf1, v1, o[nt], 0, 0, 0);
      }
      __syncthreads();  // drains vmcnt (next tile staged) + frees buf for overwrite
      cur ^= 1;
    }

    // ---- epilogue: normalize + store 16 q-rows/wave ----
#pragma unroll
    for (int r = 0; r < 4; ++r) {
      const int q = qrow0 + lg * 4 + r;
      const float inv = 1.f / lrun[r];
      u16* op = out + ((size_t)(bb * SEQ + q)) * HID + hh * HD + lr;
#pragma unroll
      for (int nt = 0; nt < 8; ++nt)
        op[nt * 16] = f2bf(o[nt][r] * inv);
    }
  }
}

extern "C" void kernel_launch(void* const* d_in, const int* in_sizes, int n_in,
                              void* d_out, int out_size, void* d_ws, size_t ws_size,
                              hipStream_t stream) {
  (void)in_sizes; (void)n_in; (void)out_size; (void)ws_size;
  const float* x   = (const float*)d_in[0];
  const int*   pos = (const int*)d_in[1];
  // d_in[2] = mask: causal tril by construction — handled analytically
  const float* wq  = (const float*)d_in[3];
  const float* wk  = (const float*)d_in[4];
  const float* wv  = (const float*)d_in[5];
  const float* wo  = (const float*)d_in[6];
  const float* asc = (const float*)d_in[7];
  const float* fsc = (const float*)d_in[8];
  const float* w1  = (const float*)d_in[9];
  const float* w3  = (const float*)d_in[10];
  const float* w2  = (const float*)d_in[11];
  float* out = (float*)d_out;

  // workspace carve (130 MB total)
  char* ws = (char*)d_ws;
  u16* qb = (u16*)ws; ws += (size_t)MROWS * HID * 2;   // Q [B,H,S,D]
  u16* kb = (u16*)ws; ws += (size_t)MROWS * HID * 2;   // K [B,H,S,D]
  u16* vb = (u16*)ws; ws += (size_t)MROWS * HID * 2;   // V^T [B,H,D,S]
  u16* xb = (u16*)ws; ws += (size_t)MROWS * HID * 2;   // x_norm / attn_out / ff (bf16)
  u16* gb = (u16*)ws; ws += (size_t)MROWS * FF * 2;    // g1 / u (bf16)
  u16* wb = (u16*)ws; ws += (size_t)FF * HID * 2;      // current transposed weight (bf16)

  dim3 b256(256);

  rmsnorm_k<<<MROWS, b256, 0, stream>>>(x, asc, xb);

  transpose_cvt_k<<<dim3(HID/32, HID/32), b256, 0, stream>>>(wq, wb, HID, HID);
  gemm_k<1><<<dim3(HID/128, MROWS/128), b256, 0, stream>>>(xb, wb, HID, HID, nullptr, nullptr, qb);
  transpose_cvt_k<<<dim3(HID/32, HID/32), b256, 0, stream>>>(wk, wb, HID, HID);
  gemm_k<1><<<dim3(HID/128, MROWS/128), b256, 0, stream>>>(xb, wb, HID, HID, nullptr, nullptr, kb);
  transpose_cvt_k<<<dim3(HID/32, HID/32), b256, 0, stream>>>(wv, wb, HID, HID);
  gemm_k<5><<<dim3(HID/128, MROWS/128), b256, 0, stream>>>(xb, wb, HID, HID, nullptr, nullptr, vb);

  rope_k<<<(NB*NHD*SEQ*(HD/2))/256, b256, 0, stream>>>(qb, pos);
  rope_k<<<(NB*NHD*SEQ*(HD/2))/256, b256, 0, stream>>>(kb, pos);

  attn_k<<<dim3(512), b256, 0, stream>>>(qb, kb, vb, xb);

  transpose_cvt_k<<<dim3(HID/32, HID/32), b256, 0, stream>>>(wo, wb, HID, HID);
  gemm_k<2><<<dim3(HID/128, MROWS/128), b256, 0, stream>>>(xb, wb, HID, HID, x, nullptr, out);  // h

  rmsnorm_k<<<MROWS, b256, 0, stream>>>(out, fsc, xb);  // ff

  transpose_cvt_k<<<dim3(FF/32, HID/32), b256, 0, stream>>>(w1, wb, HID, FF);
  gemm_k<3><<<dim3(FF/128, MROWS/128), b256, 0, stream>>>(xb, wb, FF, HID, nullptr, nullptr, gb);  // silu(ff@w1)
  transpose_cvt_k<<<dim3(FF/32, HID/32), b256, 0, stream>>>(w3, wb, HID, FF);
  gemm_k<4><<<dim3(FF/128, MROWS/128), b256, 0, stream>>>(xb, wb, FF, HID, nullptr, gb, gb);      // u = silu*g3
  transpose_cvt_k<<<dim3(HID/32, FF/32), b256, 0, stream>>>(w2, wb, FF, HID);
  gemm_k<2><<<dim3(HID/128, MROWS/128), b256, 0, stream>>>(gb, wb, HID, FF, out, nullptr, out);   // out = h + u@w2
}